// Round 5
// baseline (173.002 us; speedup 1.0000x reference)
//
#include <hip/hip_runtime.h>
#include <math.h>

#define L 64
#define D 512
#define E 8
#define F 256
#define NEG_INF -1e30f

// ---------- proj stage A: partial over 16-wide o-chunks (grid: E*32, 512 thr) ----------
__global__ void projA_kernel(const float* __restrict__ Wk, const float* __restrict__ q,
                             float* __restrict__ part) {
    const int e = blockIdx.x >> 5, oc = blockIdx.x & 31;
    const int d = threadIdx.x;
    const float* wb = Wk + ((size_t)e * D + oc * 16) * D + d;
    const float* qb = q + e * D + oc * 16;
    float acc = 0.f;
    #pragma unroll
    for (int o = 0; o < 16; ++o) acc += wb[(size_t)o * D] * qb[o];
    part[(size_t)blockIdx.x * D + d] = acc;
}

// ---------- prep2: fused proj-combine (blocks 0..7) + trans_W transpose (8..263) ----------
__global__ void prep2_kernel(const float* __restrict__ part, const float* __restrict__ W,
                             float* __restrict__ proj, float* __restrict__ wT) {
    const int b = blockIdx.x;
    if (b < 8) {
        const int i = b * 512 + threadIdx.x;      // i = e*D + d
        const int e = i >> 9, d = i & (D - 1);
        float s = 0.f;
        #pragma unroll
        for (int oc = 0; oc < 32; ++oc) s += part[(size_t)(e * 32 + oc) * D + d];
        proj[i] = s;
    } else {
        const int i = (b - 8) * 512 + threadIdx.x;   // 0..D*F-1
        const int f = i & (F - 1), d = i >> 8;
        wT[(size_t)d * F + f] = W[(size_t)f * D + d];
    }
}

// ---------- gvpv: per-vocab fold. gvpv[v][0..7]=table[v]·gate_W[e], [8..15]=table[v]·proj[e] ----------
// One 102MB sequential pass over the table; wave per vocab row.
__launch_bounds__(512, 8)
__global__ void gvpv_kernel(const float* __restrict__ table,
                            const float* __restrict__ gate_W,
                            const float* __restrict__ proj,
                            float* __restrict__ gvpv, int V) {
    const int lane = threadIdx.x & 63;
    const int wv   = threadIdx.x >> 6;
    const int v    = blockIdx.x * 8 + wv;
    if (v >= V) return;
    const float4* row = (const float4*)(table + (size_t)v * D);
    float4 r0 = row[lane], r1 = row[lane + 64];
    float p[16];
    #pragma unroll
    for (int t = 0; t < 16; ++t) {
        const float* wsrc = (t < 8) ? (gate_W + t * D) : (proj + (t - 8) * D);
        const float4* w4 = (const float4*)wsrc;
        float4 w0 = w4[lane], w1 = w4[lane + 64];
        p[t] = r0.x*w0.x + r0.y*w0.y + r0.z*w0.z + r0.w*w0.w
             + r1.x*w1.x + r1.y*w1.y + r1.z*w1.z + r1.w*w1.w;
    }
    #pragma unroll
    for (int t = 0; t < 16; ++t) {
        float s = p[t];
        #pragma unroll
        for (int off = 32; off; off >>= 1) s += __shfl_xor(s, off, 64);
        p[t] = s;                               // all lanes hold the full dot
    }
    float outv = p[0];
    #pragma unroll
    for (int t = 1; t < 16; ++t) outv = (lane == t) ? p[t] : outv;   // static select chain
    if (lane < 16) gvpv[(size_t)v * 16 + lane] = outv;
}

// ---------- row2: prefix (gate/top2/softmax from gvpv) + streaming weighted-sum gather ----------
__launch_bounds__(512, 8)   // cap 64 VGPR -> 8 waves/SIMD, 4 blocks/CU
__global__ void row2_kernel(const int* __restrict__ sample,
                            const float* __restrict__ emb_table,
                            const float* __restrict__ gvpv,
                            const float* __restrict__ gate_b,
                            float* __restrict__ pooled) {
    __shared__ float red[8][D];       // 16 KiB cross-wave reduce
    __shared__ float pvs[L][8];       // 2 KiB per-token pv
    __shared__ float cf[L];
    __shared__ int   idx_s[L];

    const int tid = threadIdx.x, lane = tid & 63, wv = tid >> 6;
    const int n = blockIdx.x;

    if (wv == 0) {
        // ---- prefix on wave 0: 64 lanes = 64 tokens ----
        int ix = sample[n * L + lane];
        idx_s[lane] = ix;
        float m = (ix != 0) ? 1.f : 0.f;        // PAD==0
        const float4* gp = (const float4*)(gvpv + (size_t)ix * 16);
        float4 g0 = gp[0], g1 = gp[1], q0 = gp[2], q1 = gp[3];
        ((float4*)pvs[lane])[0] = q0;
        ((float4*)pvs[lane])[1] = q1;

        float q[8] = {m*g0.x, m*g0.y, m*g0.z, m*g0.w, m*g1.x, m*g1.y, m*g1.z, m*g1.w};
        #pragma unroll
        for (int e = 0; e < 8; ++e) {
            float s = q[e];
            #pragma unroll
            for (int off = 32; off; off >>= 1) s += __shfl_xor(s, off, 64);
            q[e] = s;                            // full gate-dot sum on all lanes
        }
        float gs[8];
        #pragma unroll
        for (int e = 0; e < 8; ++e) gs[e] = q[e] * (1.f / 64.f) + gate_b[e];

        // top-2, first-index tie-break (computed redundantly & identically on all lanes)
        int b0 = 0; float v0 = gs[0];
        #pragma unroll
        for (int e = 1; e < 8; ++e) { if (gs[e] > v0) { v0 = gs[e]; b0 = e; } }
        int b1 = -1; float v1 = -3.4e38f;
        #pragma unroll
        for (int e = 0; e < 8; ++e) { if (e != b0 && gs[e] > v1) { v1 = gs[e]; b1 = e; } }
        float ex = expf(v1 - v0), inv = 1.f / (1.f + ex);
        float w0 = inv, w1 = ex * inv;

        float cnt = m;
        #pragma unroll
        for (int off = 32; off; off >>= 1) cnt += __shfl_xor(cnt, off, 64);

        float s0 = (m != 0.f) ? pvs[lane][b0] : NEG_INF;
        float s1 = (m != 0.f) ? pvs[lane][b1] : NEG_INF;
        float m0 = s0, m1 = s1;
        #pragma unroll
        for (int off = 32; off; off >>= 1) {
            m0 = fmaxf(m0, __shfl_xor(m0, off, 64));
            m1 = fmaxf(m1, __shfl_xor(m1, off, 64));
        }
        float e0 = expf(s0 - m0), e1 = expf(s1 - m1);
        float t0 = e0, t1 = e1;
        #pragma unroll
        for (int off = 32; off; off >>= 1) {
            t0 += __shfl_xor(t0, off, 64);
            t1 += __shfl_xor(t1, off, 64);
        }
        float c = w0 * (e0 / t0) + w1 * (e1 / t1);
        cf[lane] = (cnt == 0.f) ? 0.f : c;       // allpad -> pooled 0
    }
    __syncthreads();

    // ---- streaming weighted sum: wave wv handles tokens wv*8..wv*8+7 ----
    float4 acc0 = {0,0,0,0}, acc1 = {0,0,0,0};
    #pragma unroll
    for (int j = 0; j < 8; ++j) {
        const int l = wv * 8 + j;
        const float4* src = (const float4*)(emb_table + (size_t)idx_s[l] * D);
        float cj = cf[l];                        // wave-uniform LDS broadcast
        float4 x0 = src[lane], x1 = src[lane + 64];
        acc0.x += cj*x0.x; acc0.y += cj*x0.y; acc0.z += cj*x0.z; acc0.w += cj*x0.w;
        acc1.x += cj*x1.x; acc1.y += cj*x1.y; acc1.z += cj*x1.z; acc1.w += cj*x1.w;
    }
    ((float4*)red[wv])[lane]      = acc0;
    ((float4*)red[wv])[lane + 64] = acc1;
    __syncthreads();

    float a = 0.f;
    #pragma unroll
    for (int w = 0; w < 8; ++w) a += red[w][tid];
    pooled[(size_t)n * D + tid] = a;
}

// ---------- out_kernel: gelu(pooled @ wT + b); wave handles 2 rows ----------
__launch_bounds__(256, 4)
__global__ void out_kernel(const float* __restrict__ pooled,
                           const float* __restrict__ wT,     // [D][F]
                           const float* __restrict__ trans_b,
                           float* __restrict__ out) {
    __shared__ float pl[8 * D];             // 16 KiB
    const int tid  = threadIdx.x;
    const int lane = tid & 63;
    const int w    = tid >> 6;              // wave -> rows 2w, 2w+1
    const int n0   = blockIdx.x * 8;

    {
        const float4* src = (const float4*)(pooled + (size_t)n0 * D);
        float4* dst = (float4*)pl;
        #pragma unroll
        for (int i = 0; i < 4; ++i) dst[tid + 256 * i] = src[tid + 256 * i];
    }
    __syncthreads();

    const float* pl0 = pl + (2 * w) * D;
    const float* pl1 = pl0 + D;
    const float4* wT4 = (const float4*)wT;  // [D][F/4]
    float4 acc0 = {0.f,0.f,0.f,0.f}, acc1 = {0.f,0.f,0.f,0.f};
    #pragma unroll 4
    for (int d = 0; d < D; ++d) {
        float4 wt = wT4[d * 64 + lane];     // coalesced 16B/lane
        float p0 = pl0[d], p1 = pl1[d];     // LDS broadcast
        acc0.x += p0*wt.x; acc0.y += p0*wt.y; acc0.z += p0*wt.z; acc0.w += p0*wt.w;
        acc1.x += p1*wt.x; acc1.y += p1*wt.y; acc1.z += p1*wt.z; acc1.w += p1*wt.w;
    }

    float4 b4 = ((const float4*)trans_b)[lane];
    float4 o0, o1;
    #define GELU(v) (0.5f * (v) * (1.f + erff((v) * 0.70710678118654752f)))
    o0.x = GELU(acc0.x + b4.x); o0.y = GELU(acc0.y + b4.y);
    o0.z = GELU(acc0.z + b4.z); o0.w = GELU(acc0.w + b4.w);
    o1.x = GELU(acc1.x + b4.x); o1.y = GELU(acc1.y + b4.y);
    o1.z = GELU(acc1.z + b4.z); o1.w = GELU(acc1.w + b4.w);
    #undef GELU
    ((float4*)(out + (size_t)(n0 + 2 * w) * F))[lane]     = o0;
    ((float4*)(out + (size_t)(n0 + 2 * w + 1) * F))[lane] = o1;
}

extern "C" void kernel_launch(void* const* d_in, const int* in_sizes, int n_in,
                              void* d_out, int out_size, void* d_ws, size_t ws_size,
                              hipStream_t stream) {
    const int*   sample    = (const int*)d_in[0];
    const float* emb_table = (const float*)d_in[1];
    const float* expert_q  = (const float*)d_in[2];
    const float* expert_Wk = (const float*)d_in[3];
    const float* gate_W    = (const float*)d_in[4];
    const float* gate_b    = (const float*)d_in[5];
    const float* trans_W   = (const float*)d_in[6];
    const float* trans_b   = (const float*)d_in[7];
    float* out = (float*)d_out;

    const int N = in_sizes[0] / L;                 // B*T = 2048
    const int V = in_sizes[1] / D;                 // vocab = 50000

    float* proj   = (float*)d_ws;                  // E*D            = 16 KB
    float* pooled = proj + E * D;                  // N*D            = 4 MB
    float* part   = pooled + (size_t)N * D;        // E*32*D         = 512 KB
    float* wT     = part + E * 32 * D;             // D*F            = 512 KB
    float* gvpv   = wT + (size_t)D * F;            // V*16           = 3.2 MB
    (void)ws_size; (void)n_in; (void)out_size;

    projA_kernel<<<E * 32, D, 0, stream>>>(expert_Wk, expert_q, part);
    prep2_kernel<<<8 + (D * F) / 512, 512, 0, stream>>>(part, trans_W, proj, wT);
    gvpv_kernel<<<(V + 7) / 8, 512, 0, stream>>>(emb_table, gate_W, proj, gvpv, V);
    row2_kernel<<<N, 512, 0, stream>>>(sample, emb_table, gvpv, gate_b, pooled);
    out_kernel<<<N / 8, 256, 0, stream>>>(pooled, wT, trans_b, out);
}